// Round 1
// 1135.292 us; speedup vs baseline: 1.0965x; 1.0965x over previous
//
#include <hip/hip_runtime.h>
#include <hip/hip_bf16.h>

// Round 8: replace the 128x128 2-barrier-per-K-step GEMM (MfmaUtil 22.7%,
// VALUBusy 34.6%, HBM 16% -> latency-bound on the per-iter vmcnt(0) barrier
// drain) with the 256x256 8-phase counted-vmcnt schedule (T2 swizzle + T3/T4
// counted vmcnt + T5 setprio). 512 threads = 8 waves (2M x 4N), BK=64 per
// K-tile, 2 K-tiles per iteration, 128 KiB LDS double buffer. Stages are
// issued 5-7 half-tiles ahead of consumption; s_waitcnt vmcnt(4) only at
// phase-4/8 boundaries, vmcnt(0) only in the last iteration's drain.
// Per-output-element accumulation order (K-tile ascending, k-half 0 then 1)
// is identical to r7 -> numerics unchanged.
// f32 in/out per reference; bf16 MFMA internally. B=8, N=2048, DA=768, DB=1024.

#define AS1 __attribute__((address_space(1)))
#define AS3 __attribute__((address_space(3)))

typedef __attribute__((ext_vector_type(8))) short bf16x8;
typedef __attribute__((ext_vector_type(4))) float f32x4;

using bf = __hip_bfloat16;

// ---------------- unified 256x256 8-phase GEMM ----------------
// C = alpha * A[M,K] @ BT[Nc,K]^T.
// nseg==1: (+bias)(+resid32/resid16) -> C16 and/or C32, ldc=Nc, tstore bit0.
// nseg>1 : 1024-col segments -> {C16,C16b,C16c} w/ biases {bias,biasB,biasC};
//          tstore bit s stores segment s transposed per 2048-row batch.
// Constraints: M%256==0, Nc%256==0, K%128==0 (all call sites satisfy).
__global__ __launch_bounds__(512, 1) void gemm256(
    const bf* __restrict__ A, const bf* __restrict__ BT,
    const float* __restrict__ bias, const float* __restrict__ biasB,
    const float* __restrict__ biasC,
    const float* __restrict__ resid32, const bf* __restrict__ resid16,
    bf* __restrict__ C16, bf* __restrict__ C16b, bf* __restrict__ C16c,
    float* __restrict__ C32,
    int M, int Nc, int K, float alpha,
    long sA, long sB, long sC, int tstore, int nseg)
{
    // [slot:2][region:4][row:128][col:64] bf16 = 128 KiB.
    // region 0 = A rows [0,128), 1 = B rows [0,128), 2 = A rows [128,256),
    // region 3 = B rows [128,256). slot = K-tile & 1.
    __shared__ __align__(16) char lds[131072];

    const int tid  = threadIdx.x;
    const int wave = tid >> 6;        // 0..7
    const int lane = tid & 63;
    const int wm = wave >> 2;         // 0..1 : M half (128 rows)
    const int wn = wave & 3;          // 0..3 : N quarter (64 cols)
    const int m0 = blockIdx.y * 256;
    const int n0 = blockIdx.x * 256;
    const long zC = (long)blockIdx.z * sC;
    A  += (long)blockIdx.z * sA;
    BT += (long)blockIdx.z * sB;

    const int fl = lane & 15, qd = lane >> 4;
    const int sr = lane >> 3;             // staging sub-row within 8-row group
    const int scn = (lane & 7) ^ sr;      // pre-swizzled global chunk
    const long ldb = (long)K * 2;

    // Staging: each wave covers region-rows [wave*16, wave*16+16), 2 issues
    // of 8 rows. LDS dest linear (global_load_lds constraint); source chunk
    // pre-swizzled so LDS slot s of row R holds global chunk s ^ (R&7).
    const char* gA = (const char*)A  + (long)(m0 + wave * 16 + sr) * ldb + scn * 16;
    const char* gB = (const char*)BT + (long)(n0 + wave * 16 + sr) * ldb + scn * 16;

    auto stage_ht = [&](int s) {   // s = half-tile position: tile s>>2, region s&3
        const int t = s >> 2, r = s & 3;
        const char* g = ((r & 1) ? gB : gA) + (long)((r >> 1) * 128) * ldb + (long)t * 128;
        char* l = lds + ((t & 1) * 65536) + r * 16384 + wave * 2048;
        __builtin_amdgcn_global_load_lds((const AS1 void*)g,               (AS3 void*)l,          16, 0, 0);
        __builtin_amdgcn_global_load_lds((const AS1 void*)(g + 8 * ldb),   (AS3 void*)(l + 1024), 16, 0, 0);
    };

    // Fragment reads: row R in region, k-chunk c=(h<<2)|qd at slot c^(R&7);
    // R&7 == fl&7 for all fragment rows.
    const int xo = fl & 7;
    const int so0 = ((0 | qd) ^ xo) * 16;   // k-half 0 byte slot
    const int so1 = ((4 | qd) ^ xo) * 16;   // k-half 1 byte slot
    const char* Abase = lds + (wm ? 2 : 0) * 16384 + fl * 128;
    const char* Bbase = lds + ((wn >> 1) ? 3 : 1) * 16384 + (wn & 1) * 64 * 128 + fl * 128;

    f32x4 acc[8][4];
#pragma unroll
    for (int i = 0; i < 8; ++i)
#pragma unroll
        for (int j = 0; j < 4; ++j)
            acc[i][j] = (f32x4){0.f, 0.f, 0.f, 0.f};

    bf16x8 afr[2][4][2];   // [mq][Mfrag][khalf]
    bf16x8 bfr[2][2][2];   // [nq][Nfrag][khalf]

#define READ_A(mq, SL) { const char* pA_ = Abase + (SL) * 65536 + (mq) * 8192; \
    _Pragma("unroll") for (int f_ = 0; f_ < 4; ++f_) { \
        afr[mq][f_][0] = *(const bf16x8*)(pA_ + f_ * 2048 + so0); \
        afr[mq][f_][1] = *(const bf16x8*)(pA_ + f_ * 2048 + so1); } }

#define READ_B(nq, SL) { const char* pB_ = Bbase + (SL) * 65536 + (nq) * 4096; \
    _Pragma("unroll") for (int g_ = 0; g_ < 2; ++g_) { \
        bfr[nq][g_][0] = *(const bf16x8*)(pB_ + g_ * 2048 + so0); \
        bfr[nq][g_][1] = *(const bf16x8*)(pB_ + g_ * 2048 + so1); } }

#define MFMA_Q(mq, nq) { \
    __builtin_amdgcn_s_setprio(1); \
    _Pragma("unroll") for (int f_ = 0; f_ < 4; ++f_) \
    _Pragma("unroll") for (int g_ = 0; g_ < 2; ++g_) { \
        acc[(mq)*4+f_][(nq)*2+g_] = __builtin_amdgcn_mfma_f32_16x16x32_bf16( \
            afr[mq][f_][0], bfr[nq][g_][0], acc[(mq)*4+f_][(nq)*2+g_], 0, 0, 0); \
        acc[(mq)*4+f_][(nq)*2+g_] = __builtin_amdgcn_mfma_f32_16x16x32_bf16( \
            afr[mq][f_][1], bfr[nq][g_][1], acc[(mq)*4+f_][(nq)*2+g_], 0, 0, 0); } \
    __builtin_amdgcn_s_setprio(0); }

#define BAR() __builtin_amdgcn_s_barrier()
#define VMCNT4() asm volatile("s_waitcnt vmcnt(4)" ::: "memory")
#define VMCNT0() asm volatile("s_waitcnt vmcnt(0)" ::: "memory")
#define STG(S) { if ((S) < nht) stage_ht(S); }

    const int NT    = K >> 6;     // K-tiles (even at all call sites)
    const int niter = NT >> 1;
    const int nht   = NT << 2;

    // Prologue: tile0 {A0,B0,A1,B1} + tile1 {A0,B0}; tile0 must be landed.
#pragma unroll
    for (int s = 0; s < 6; ++s) stage_ht(s);
    VMCNT4();
    BAR();

    for (int I = 0; I < niter; ++I) {
        const int s0 = 8 * I + 6;           // rolling stage cursor
        const bool last = (I == niter - 1);
        // ---- K-tile 2I (slot 0) ----
        // ph1: frags (mq0,nq0); stage tile 2I+1.A1 (slot1)
        READ_A(0, 0); READ_B(0, 0); STG(s0 + 0); BAR(); MFMA_Q(0, 0); BAR();
        // ph2: frags (mq1,nq1); stage tile 2I+1.B1
        READ_A(1, 0); READ_B(1, 0); STG(s0 + 1); BAR(); MFMA_Q(1, 1); BAR();
        // ph3: stage tile 2I+2.A0 (slot0; its reads finished at ph2)
        STG(s0 + 2); BAR(); MFMA_Q(0, 1); BAR();
        // ph4: stage tile 2I+2.B0; boundary: tile 2I+1 must be landed
        STG(s0 + 3); BAR(); MFMA_Q(1, 0);
        if (last) { VMCNT0(); } else { VMCNT4(); }
        BAR();
        // ---- K-tile 2I+1 (slot 1) ----
        READ_A(0, 1); READ_B(0, 1); STG(s0 + 4); BAR(); MFMA_Q(0, 0); BAR();
        READ_A(1, 1); READ_B(1, 1); STG(s0 + 5); BAR(); MFMA_Q(1, 1); BAR();
        STG(s0 + 6); BAR(); MFMA_Q(0, 1); BAR();
        STG(s0 + 7); BAR(); MFMA_Q(1, 0);
        if (!last) { VMCNT4(); }
        BAR();
    }

    // Epilogue: C/D layout col = lane&15, row = qd*4 + r (verified m89/m91).
    if (nseg == 1) {
        const long ldc = Nc;
#pragma unroll
        for (int i = 0; i < 8; ++i) {
#pragma unroll
            for (int j = 0; j < 4; ++j) {
#pragma unroll
                for (int r = 0; r < 4; ++r) {
                    const int row = m0 + wm * 128 + i * 16 + qd * 4 + r;
                    const int col = n0 + wn * 64 + j * 16 + fl;
                    float v = acc[i][j][r] * alpha;
                    if (bias) v += bias[col];
                    if (tstore & 1) {
                        const long idx = (long)(row >> 11) * ((long)Nc * 2048)
                                       + (long)col * 2048 + (row & 2047);
                        C16[idx] = __float2bfloat16(v);
                    } else {
                        const long idx = zC + (long)row * ldc + col;
                        if (resid32) v += resid32[idx];
                        if (resid16) v += __bfloat162float(resid16[idx]);
                        if (C16) C16[idx] = __float2bfloat16(v);
                        if (C32) C32[idx] = v;
                    }
                }
            }
        }
    } else {
        const int seg = n0 >> 10;
        bf* dst = (seg == 0) ? C16 : ((seg == 1) ? C16b : C16c);
        const float* bseg = (seg == 0) ? bias : ((seg == 1) ? biasB : biasC);
        const int trans = (tstore >> seg) & 1;
        const int cb = n0 & 1023;
#pragma unroll
        for (int i = 0; i < 8; ++i) {
#pragma unroll
            for (int j = 0; j < 4; ++j) {
#pragma unroll
                for (int r = 0; r < 4; ++r) {
                    const int row = m0 + wm * 128 + i * 16 + qd * 4 + r;
                    const int col = cb + wn * 64 + j * 16 + fl;
                    float v = acc[i][j][r] * alpha + bseg[col];
                    const long idx = trans
                        ? (long)(row >> 11) * (1024L * 2048) + (long)col * 2048 + (row & 2047)
                        : (long)row * 1024 + col;
                    dst[idx] = __float2bfloat16(v);
                }
            }
        }
    }
#undef READ_A
#undef READ_B
#undef MFMA_Q
#undef BAR
#undef VMCNT4
#undef VMCNT0
#undef STG
}

// elementwise f32 -> bf16, n must be a multiple of 8
__global__ __launch_bounds__(256) void cast_f32_bf16(
    const float* __restrict__ in, bf* __restrict__ out, long n)
{
    long i = ((long)blockIdx.x * 256 + threadIdx.x) * 8;
    if (i >= n) return;
    float4 a = *(const float4*)(in + i);
    float4 b = *(const float4*)(in + i + 4);
    bf o[8] = {__float2bfloat16(a.x), __float2bfloat16(a.y),
               __float2bfloat16(a.z), __float2bfloat16(a.w),
               __float2bfloat16(b.x), __float2bfloat16(b.y),
               __float2bfloat16(b.z), __float2bfloat16(b.w)};
    *(bf16x8*)(out + i) = *(bf16x8*)o;
}

// W[R,C] f32 -> WT[C,R] bf16
__global__ __launch_bounds__(256) void transpose_f32_bf16(
    const float* __restrict__ in, bf* __restrict__ out, int R, int C)
{
    __shared__ bf t[32][33];
    const int c0 = blockIdx.x * 32, r0 = blockIdx.y * 32;
    const int tx = threadIdx.x, ty = threadIdx.y;
#pragma unroll
    for (int i = ty; i < 32; i += 8)
        t[i][tx] = __float2bfloat16(in[(long)(r0 + i) * C + c0 + tx]);
    __syncthreads();
#pragma unroll
    for (int i = ty; i < 32; i += 8)
        out[(long)(c0 + i) * R + r0 + tx] = t[tx][i];
}

// In-place row softmax over 2048 bf16 cols; one 256-thread block per row.
__global__ __launch_bounds__(256) void softmax_rows(bf* __restrict__ S)
{
    const long row = blockIdx.x;
    bf* p = S + row * 2048;
    const int tx = threadIdx.x;

    float v[8];
    float m = -3.0e38f;
#pragma unroll
    for (int i = 0; i < 8; i++) {
        v[i] = __bfloat162float(p[tx + 256 * i]);
        m = fmaxf(m, v[i]);
    }
    __shared__ float red[4];
#pragma unroll
    for (int o = 1; o < 64; o <<= 1) m = fmaxf(m, __shfl_xor(m, o, 64));
    if ((tx & 63) == 0) red[tx >> 6] = m;
    __syncthreads();
    m = fmaxf(fmaxf(red[0], red[1]), fmaxf(red[2], red[3]));

    float s = 0.f;
#pragma unroll
    for (int i = 0; i < 8; i++) { v[i] = __expf(v[i] - m); s += v[i]; }
#pragma unroll
    for (int o = 1; o < 64; o <<= 1) s += __shfl_xor(s, o, 64);
    __syncthreads();
    if ((tx & 63) == 0) red[tx >> 6] = s;
    __syncthreads();
    const float inv = 1.0f / (red[0] + red[1] + red[2] + red[3]);
#pragma unroll
    for (int i = 0; i < 8; i++) p[tx + 256 * i] = __float2bfloat16(v[i] * inv);
}

extern "C" void kernel_launch(void* const* d_in, const int* in_sizes, int n_in,
                              void* d_out, int out_size, void* d_ws, size_t ws_size,
                              hipStream_t stream)
{
    const int Bb = 8, Nn = 2048, DA = 768, DB = 1024;
    const long Mt = (long)Bb * Nn;   // 16384 tokens

    const float* x_a   = (const float*)d_in[0];
    const float* x_b   = (const float*)d_in[1];
    const float* sa_wq = (const float*)d_in[2];  const float* sa_bq = (const float*)d_in[3];
    const float* sa_wk = (const float*)d_in[4];  const float* sa_bk = (const float*)d_in[5];
    const float* sa_wv = (const float*)d_in[6];  const float* sa_bv = (const float*)d_in[7];
    const float* sa_wo = (const float*)d_in[8];  const float* sa_bo = (const float*)d_in[9];
    const float* ca_wq = (const float*)d_in[10]; const float* ca_bq = (const float*)d_in[11];
    const float* ca_wk = (const float*)d_in[12]; const float* ca_bk = (const float*)d_in[13];
    const float* ca_wv = (const float*)d_in[14]; const float* ca_bv = (const float*)d_in[15];
    const float* ca_wo = (const float*)d_in[16]; const float* ca_bo = (const float*)d_in[17];
    float* out = (float*)d_out;
    (void)in_sizes; (void)n_in; (void)out_size; (void)ws_size;

    // workspace carve-up (256B aligned): peak 207.5 MB (r3 layout proven)
    char* ws = (char*)d_ws;
    size_t off = 0;
    auto alloc = [&](size_t bytes) -> bf* {
        bf* p = (bf*)(ws + off);
        off += (bytes + 255) & ~(size_t)255;
        return p;
    };
    bf* wqkvT = alloc((size_t)3 * DB * DB * 2);  // [3072,1024] concat q,k,v
    bf* woT   = alloc((size_t)DB * DB * 2);
    bf* cwqT  = alloc((size_t)DB * DA * 2);      // [1024,768]
    bf* ckvT  = alloc((size_t)2 * DB * DB * 2);  // [2048,1024] concat k,v
    bf* cwoT  = alloc((size_t)DB * DB * 2);
    bf* slA   = alloc((size_t)Mt * DB * 2);      // xbB -> xaB -> VcT
    bf* slQ   = alloc((size_t)Mt * DB * 2);      // Q   -> Xb
    bf* slK   = alloc((size_t)Mt * DB * 2);      // K   -> attn -> Qc
    bf* slV   = alloc((size_t)Mt * DB * 2);      // VT  -> Kc
    bf* S     = alloc((size_t)Bb * Nn * Nn * 2);

    const dim3 tb(32, 8);
    const dim3 blk(256);
    const dim3 blk5(512);
    const long sQ = (long)Nn * DB;
    const long sS = (long)Nn * Nn;
    const float* nf = nullptr;
    const bf*    nb = nullptr;
    bf*          no = nullptr;

    // ---- ingestion: weight transposes (f32 -> bf16), concat layouts ----
    transpose_f32_bf16<<<dim3(DB/32, DB/32), tb, 0, stream>>>(sa_wq, wqkvT,                 DB, DB);
    transpose_f32_bf16<<<dim3(DB/32, DB/32), tb, 0, stream>>>(sa_wk, wqkvT + (size_t)DB*DB, DB, DB);
    transpose_f32_bf16<<<dim3(DB/32, DB/32), tb, 0, stream>>>(sa_wv, wqkvT + (size_t)2*DB*DB, DB, DB);
    transpose_f32_bf16<<<dim3(DB/32, DB/32), tb, 0, stream>>>(sa_wo, woT,  DB, DB);
    transpose_f32_bf16<<<dim3(DB/32, DA/32), tb, 0, stream>>>(ca_wq, cwqT, DA, DB);
    transpose_f32_bf16<<<dim3(DB/32, DB/32), tb, 0, stream>>>(ca_wk, ckvT,                 DB, DB);
    transpose_f32_bf16<<<dim3(DB/32, DB/32), tb, 0, stream>>>(ca_wv, ckvT + (size_t)DB*DB, DB, DB);
    transpose_f32_bf16<<<dim3(DB/32, DB/32), tb, 0, stream>>>(ca_wo, cwoT, DB, DB);

    // ---- self-attention ----
    cast_f32_bf16<<<dim3((unsigned)(Mt * DB / 8 / 256)), blk, 0, stream>>>(x_b, slA, Mt * DB);
    // fused QKV: Q->slQ, K->slK, V->slV (transposed per batch)
    gemm256<<<dim3(3*DB/256, Mt/256, 1), blk5, 0, stream>>>(
        slA, wqkvT, sa_bq, sa_bk, sa_bv, nf, nb, slQ, slK, slV, nullptr,
        (int)Mt, 3*DB, DB, 1.0f, 0, 0, 0, 0b100, 3);
    // scores = (Q @ K^T) / 32
    gemm256<<<dim3(Nn/256, Nn/256, Bb), blk5, 0, stream>>>(
        slQ, slK, nf, nf, nf, nf, nb, S, no, no, nullptr,
        Nn, Nn, DB, 0.03125f, sQ, sQ, sS, 0, 1);
    softmax_rows<<<dim3((unsigned)(Bb * Nn)), blk, 0, stream>>>(S);
    // attn = P @ V (VT as B^T) -> slK (K dead)
    gemm256<<<dim3(DB/256, Nn/256, Bb), blk5, 0, stream>>>(
        S, slV, nf, nf, nf, nf, nb, slK, no, no, nullptr,
        Nn, DB, Nn, 1.0f, sS, sQ, sQ, 0, 1);
    // x_b_new = x_b(f32) + attn @ Wo + bo -> slQ (Q dead)
    gemm256<<<dim3(DB/256, Mt/256, 1), blk5, 0, stream>>>(
        slK, woT, sa_bo, nf, nf, x_b, nb, slQ, no, no, nullptr,
        (int)Mt, DB, DB, 1.0f, 0, 0, 0, 0, 1);

    // ---- cross-attention ----
    cast_f32_bf16<<<dim3((unsigned)(Mt * DA / 8 / 256)), blk, 0, stream>>>(x_a, slA, Mt * DA);
    // Qc = xa @ cwq -> slK (attn dead)   [K=768 -> 12 K-tiles, 6 iters]
    gemm256<<<dim3(DB/256, Mt/256, 1), blk5, 0, stream>>>(
        slA, cwqT, ca_bq, nf, nf, nf, nb, slK, no, no, nullptr,
        (int)Mt, DB, DA, 1.0f, 0, 0, 0, 0, 1);
    // fused cKV from Xb(slQ): Kc->slV (VT dead), Vc->slA transposed (xaB dead)
    gemm256<<<dim3(2*DB/256, Mt/256, 1), blk5, 0, stream>>>(
        slQ, ckvT, ca_bk, ca_bv, nf, nf, nb, slV, slA, no, nullptr,
        (int)Mt, 2*DB, DB, 1.0f, 0, 0, 0, 0b10, 2);
    // scores = (Qc @ Kc^T) / sqrt(768)
    gemm256<<<dim3(Nn/256, Nn/256, Bb), blk5, 0, stream>>>(
        slK, slV, nf, nf, nf, nf, nb, S, no, no, nullptr,
        Nn, Nn, DB, 0.036084391824351615f, sQ, sQ, sS, 0, 1);
    softmax_rows<<<dim3((unsigned)(Bb * Nn)), blk, 0, stream>>>(S);
    // ca_attn = P @ Vc -> slV (Kc dead)
    gemm256<<<dim3(DB/256, Nn/256, Bb), blk5, 0, stream>>>(
        S, slA, nf, nf, nf, nf, nb, slV, no, no, nullptr,
        Nn, DB, Nn, 1.0f, sS, sQ, sQ, 0, 1);
    // out(f32) = x_b_new(bf16, slQ) + ca_attn @ Wo + bo
    gemm256<<<dim3(DB/256, Mt/256, 1), blk5, 0, stream>>>(
        slV, cwoT, ca_bo, nf, nf, nf, slQ, no, no, no, out,
        (int)Mt, DB, DB, 1.0f, 0, 0, 0, 0, 1);
}